// Round 10
// baseline (455.892 us; speedup 1.0000x reference)
//
#include <hip/hip_runtime.h>
#include <hip/hip_bf16.h>
#include <math.h>

#define EMB_DIM 4096
#define INNER   1024
#define VOCAB   32000
#define NPRED   3
#define SEQ     512
#define TOKENS  1024   // B*N = 2*512

typedef __attribute__((ext_vector_type(8))) short bf16x8;
typedef __attribute__((ext_vector_type(4))) float f32x4;

__device__ inline void gload_lds16(const void* g, void* l) {
  __builtin_amdgcn_global_load_lds(
      (const __attribute__((address_space(1))) void*)g,
      (__attribute__((address_space(3))) void*)l, 16, 0, 0);
}

__device__ inline unsigned short f2bf(float f) {
  unsigned u = __float_as_uint(f);
  u += 0x7fffu + ((u >> 16) & 1u);
  return (unsigned short)(u >> 16);
}

// ---------------- f32 -> bf16 convert, x4 vectorized ----------------
__global__ void cvt_kernel(const float4* __restrict__ in, ushort4* __restrict__ out, int n4) {
  int stride = gridDim.x * blockDim.x;
  for (int i = blockIdx.x * blockDim.x + threadIdx.x; i < n4; i += stride) {
    float4 v = in[i];
    ushort4 o;
    o.x = f2bf(v.x); o.y = f2bf(v.y); o.z = f2bf(v.z); o.w = f2bf(v.w);
    out[i] = o;
  }
}

// ---------------- merged: 128x64-tile proj GEMM (blocks 0..127) + head cvt --
// (R5-verified proj part) step-0 only: K=EMB_DIM, cvt head_w[0].
__global__ __launch_bounds__(256) void proj_cvt(const __hip_bfloat16* __restrict__ A,
                                                const __hip_bfloat16* __restrict__ Bw,
                                                float* __restrict__ C, int K,
                                                const float4* __restrict__ cvsrc,
                                                ushort4* __restrict__ cvdst, int n4) {
  if (blockIdx.x >= 128) {
    for (int i = (blockIdx.x - 128) * 256 + threadIdx.x; i < n4; i += 896 * 256) {
      float4 v = cvsrc[i];
      ushort4 o;
      o.x = f2bf(v.x); o.y = f2bf(v.y); o.z = f2bf(v.z); o.w = f2bf(v.w);
      cvdst[i] = o;
    }
    return;
  }
  __shared__ char smem[12288];
  char* As = smem;           // [128][32] bf16 = 8 KB
  char* Bs = smem + 8192;    // [64][32]  bf16 = 4 KB

  const int tid  = threadIdx.x;
  const int lane = tid & 63;
  const int wave = tid >> 6;
  const int wm = wave >> 1, wn = wave & 1;

  const int bm = (blockIdx.x >> 4) * 128;   // 8 m-tiles
  const int bn = (blockIdx.x & 15) * 64;    // 16 n-tiles
  const int N = 1024;

  const char* Ag = (const char*)(A  + (size_t)(bm + (tid >> 2)) * K + (tid & 3) * 8);
  const char* Bg = (const char*)(Bw + (size_t)(bn + (tid >> 2)) * K + (tid & 3) * 8);
  const size_t rowskipA = (size_t)64 * K * 2;

  f32x4 acc[4][2] = {};

  const int fa = (wm * 64 + (lane & 15)) * 64 + (lane >> 4) * 16;
  const int fb = (wn * 32 + (lane & 15)) * 64 + (lane >> 4) * 16;

  for (int k0 = 0; k0 < K; k0 += 32) {
    gload_lds16(Ag,            As + tid * 16);
    gload_lds16(Ag + rowskipA, As + 4096 + tid * 16);
    gload_lds16(Bg,            Bs + tid * 16);
    Ag += 64; Bg += 64;
    __syncthreads();

    bf16x8 af[4], bfv[2];
#pragma unroll
    for (int m = 0; m < 4; ++m) af[m]  = *(const bf16x8*)(As + fa + m * 1024);
#pragma unroll
    for (int n = 0; n < 2; ++n) bfv[n] = *(const bf16x8*)(Bs + fb + n * 1024);
#pragma unroll
    for (int m = 0; m < 4; ++m)
#pragma unroll
      for (int n = 0; n < 2; ++n)
        acc[m][n] = __builtin_amdgcn_mfma_f32_16x16x32_bf16(af[m], bfv[n], acc[m][n], 0, 0, 0);
    __syncthreads();
  }

  const int r0 = bm + wm * 64 + (lane >> 4) * 4;
  const int c0 = bn + wn * 32 + (lane & 15);
#pragma unroll
  for (int m = 0; m < 4; ++m)
#pragma unroll
    for (int n = 0; n < 2; ++n) {
      float* Cp = C + (size_t)(r0 + m * 16) * N + (c0 + n * 16);
#pragma unroll
      for (int r = 0; r < 4; ++r)
        Cp[(size_t)r * N] = acc[m][n][r];
    }
}

// ---------------- mega: head (0..999) + proj (1000..1063) + cvt (1064..1523)
// Head: 256x128 tile, BK=32 double-buffer, 48KB LDS, 8 waves (4Mx2N), acc 64
// VGPR/wave -> __launch_bounds__(512,4) -> 2 blocks/CU co-resident. The
// co-resident block hides barrier/epilogue drains (m97/m114 mechanism) at
// R4-level B traffic (1000 blocks, 128-wide panels x4 same-XCD sharers).
__global__ __launch_bounds__(512, 4) void mega(const __hip_bfloat16* __restrict__ A,
                                               const __hip_bfloat16* __restrict__ B,
                                               float* __restrict__ C,
                                               const __hip_bfloat16* __restrict__ Pw,
                                               float* __restrict__ nsf,
                                               const float4* __restrict__ cvsrc,
                                               ushort4* __restrict__ cvdst, int n4,
                                               int mode) {
  __shared__ char smem[49152];   // A dbuf 2x16KB @0, B dbuf 2x8KB @32768
  const int tid  = threadIdx.x;
  const int lane = tid & 63;
  const int wave = tid >> 6;

  if (mode == 0 && blockIdx.x >= 1064) {
    // ---- head_w(i+1) f32 -> bf16, 460 blocks x 512 thr ----
    for (int i = (blockIdx.x - 1064) * 512 + tid; i < n4; i += 460 * 512) {
      float4 v = cvsrc[i];
      ushort4 o;
      o.x = f2bf(v.x); o.y = f2bf(v.y); o.z = f2bf(v.z); o.w = f2bf(v.w);
      cvdst[i] = o;
    }
    return;
  }

  if (mode == 0 && blockIdx.x >= 1000) {
    // ---- proj(i+1): 128x128 tile, 8 waves (2Mx4N), per-wave 64x32, K=INNER --
    char* As = smem;
    char* Bs = smem + 8192;
    const int p = blockIdx.x - 1000;
    const int bm = (p >> 3) * 128;
    const int bn = (p & 7) * 128;
    const int wm = wave >> 2, wn = wave & 3;

    const char* Ag = (const char*)(A  + (size_t)(bm + (tid >> 2)) * INNER + (tid & 3) * 8);
    const char* Bg = (const char*)(Pw + (size_t)(bn + (tid >> 2)) * INNER + (tid & 3) * 8);

    f32x4 acc[4][2] = {};
    const int fa = (wm * 64 + (lane & 15)) * 64 + (lane >> 4) * 16;
    const int fb = (wn * 32 + (lane & 15)) * 64 + (lane >> 4) * 16;

    for (int k0 = 0; k0 < INNER; k0 += 32) {
      gload_lds16(Ag, As + tid * 16);
      gload_lds16(Bg, Bs + tid * 16);
      Ag += 64; Bg += 64;
      __syncthreads();
      bf16x8 af[4], bfv[2];
#pragma unroll
      for (int m = 0; m < 4; ++m) af[m]  = *(const bf16x8*)(As + fa + m * 1024);
#pragma unroll
      for (int n = 0; n < 2; ++n) bfv[n] = *(const bf16x8*)(Bs + fb + n * 1024);
#pragma unroll
      for (int m = 0; m < 4; ++m)
#pragma unroll
        for (int n = 0; n < 2; ++n)
          acc[m][n] = __builtin_amdgcn_mfma_f32_16x16x32_bf16(af[m], bfv[n], acc[m][n], 0, 0, 0);
      __syncthreads();
    }
    const int r0 = bm + wm * 64 + (lane >> 4) * 4;
    const int c0 = bn + wn * 32 + (lane & 15);
#pragma unroll
    for (int m = 0; m < 4; ++m)
#pragma unroll
      for (int n = 0; n < 2; ++n) {
        float* Cp = nsf + (size_t)(r0 + m * 16) * INNER + (c0 + n * 16);
#pragma unroll
        for (int r = 0; r < 4; ++r)
          Cp[(size_t)r * INNER] = acc[m][n][r];
      }
    return;
  }

  // ---- head GEMM: 256x128 tile, BK=32 dbuf, 2 blocks/CU ----
  const int hid = blockIdx.x;   // 0..999
  const int K = INNER, N = VOCAB;
  const int wm = wave >> 1;     // 0..3  (M direction, 4 x 64 rows)
  const int wn = wave & 1;      // 0..1  (N direction, 2 x 64 cols)

  // chunked XCD swizzle (1000 % 8 == 0, q=125); bm-fastest: 4 consecutive wg
  // (same XCD, adjacent dispatch) share one 128-wide B panel.
  const int wg = (hid & 7) * 125 + (hid >> 3);
  const int bm = (wg & 3) * 256;
  const int bn = (wg >> 2) * 128;

  f32x4 acc[4][4] = {};

  const int sl   = (lane >> 4) ^ ((lane >> 1) & 3);
  const int aoff = (wm * 64 + (lane & 15)) * 64 + sl * 16;
  const int boff = (wn * 64 + (lane & 15)) * 64 + sl * 16;

  // A tile: 256x32 bf16 = 16KB (1024 chunks, 2/thread); B tile: 128x32 = 8KB (1/thread)
#define STAGE_AB(KT_, BUF_)                                                     \
  {                                                                             \
    _Pragma("unroll")                                                           \
    for (int c = 0; c < 2; ++c) {                                               \
      int chunk = c * 512 + tid;                                                \
      int row = chunk >> 2;                                                     \
      int s = (chunk & 3) ^ ((row >> 1) & 3);                                   \
      gload_lds16(A + (size_t)(bm + row) * K + (KT_) * 32 + s * 8,              \
                  smem + (BUF_) * 16384 + chunk * 16);                          \
    }                                                                           \
    {                                                                           \
      int row = tid >> 2;                                                       \
      int s = (tid & 3) ^ ((row >> 1) & 3);                                     \
      gload_lds16(B + (size_t)(bn + row) * K + (KT_) * 32 + s * 8,              \
                  smem + 32768 + (BUF_) * 8192 + tid * 16);                     \
    }                                                                           \
  }

  STAGE_AB(0, 0)
  STAGE_AB(1, 1)

  const int KT = K >> 5;   // 32
  for (int t = 0; t < KT; ++t) {
    const int b = t & 1;
    const char* Ab = smem + b * 16384;
    const char* Bb = smem + 32768 + b * 8192;

    // own tile-t loads (3) forced landed; tile t+1's 3 stay in flight
    asm volatile("s_waitcnt vmcnt(3)" ::: "memory");
    __builtin_amdgcn_s_barrier();

    bf16x8 af[4], bfv[4];
#pragma unroll
    for (int m = 0; m < 4; ++m) af[m]  = *(const bf16x8*)(Ab + aoff + m * 1024);
#pragma unroll
    for (int n = 0; n < 4; ++n) bfv[n] = *(const bf16x8*)(Bb + boff + n * 1024);
    asm volatile("s_waitcnt lgkmcnt(0)" ::: "memory");
    __builtin_amdgcn_sched_barrier(0);
    __builtin_amdgcn_s_barrier();          // all waves done reading buf b

    const int pk = (t + 2 < KT) ? t + 2 : KT - 1;  // clamp keeps counts uniform
    STAGE_AB(pk, b)                        // overwrite buf b (reads drained)

    __builtin_amdgcn_s_setprio(1);
#pragma unroll
    for (int m = 0; m < 4; ++m)
#pragma unroll
      for (int n = 0; n < 4; ++n)
        acc[m][n] = __builtin_amdgcn_mfma_f32_16x16x32_bf16(af[m], bfv[n], acc[m][n], 0, 0, 0);
    __builtin_amdgcn_s_setprio(0);
    __builtin_amdgcn_sched_barrier(0);
  }
  asm volatile("s_waitcnt vmcnt(0)" ::: "memory");  // drain DMA before exit

  // epilogue: C/D layout col = lane&15, row = (lane>>4)*4 + rr; wn gives 2x64 cols? (wn*64)
  const int r0 = bm + wm * 64 + (lane >> 4) * 4;
  const int c0 = bn + wn * 64 + (lane & 15);
#pragma unroll
  for (int m = 0; m < 4; ++m)
#pragma unroll
    for (int n = 0; n < 4; ++n) {
      float* Cp = C + (size_t)(r0 + m * 16) * N + (c0 + n * 16);
#pragma unroll
      for (int rr = 0; rr < 4; ++rr)
        Cp[(size_t)rr * N] = acc[m][n][rr];
    }
#undef STAGE_AB
}

// ---------------- fused: s = ns + alpha*z ; RMS-LN ; exact GELU ; -> bf16 ----
__global__ __launch_bounds__(256) void fuse_ln_gelu(const float* __restrict__ ns,
    const float* __restrict__ emb,
    const int* __restrict__ inds,
    const float* __restrict__ lnw, const float* __restrict__ lnb,
    ushort4* __restrict__ out_bf16,
    int i, float alpha)
{
  const int t = blockIdx.x;
  const int b = t >> 9, n = t & 511;
  const int idx = inds[b * (SEQ + NPRED) + n + i];

  const float4* x = (const float4*)(ns + (size_t)t * INNER);
  const float4* z = (const float4*)(emb + (size_t)idx * INNER);
  const int j = threadIdx.x;

  float4 xv = x[j], zv = z[j];
  float4 v;
  v.x = xv.x + alpha * zv.x;
  v.y = xv.y + alpha * zv.y;
  v.z = xv.z + alpha * zv.z;
  v.w = xv.w + alpha * zv.w;

  float ss = v.x * v.x + v.y * v.y + v.z * v.z + v.w * v.w;
#pragma unroll
  for (int o = 32; o > 0; o >>= 1) ss += __shfl_down(ss, o);
  __shared__ float red[4];
  if ((threadIdx.x & 63) == 0) red[threadIdx.x >> 6] = ss;
  __syncthreads();
  float total = red[0] + red[1] + red[2] + red[3];
  float r = rsqrtf(total * (1.0f / INNER) + 1e-6f);

  float4 wv = ((const float4*)lnw)[j];
  float4 bv = ((const float4*)lnb)[j];
  const float inv_sqrt2 = 0.70710678118654752f;
  ushort4 o;
  float y;
  y = v.x * r * wv.x + bv.x; o.x = f2bf(0.5f * y * (1.0f + erff(y * inv_sqrt2)));
  y = v.y * r * wv.y + bv.y; o.y = f2bf(0.5f * y * (1.0f + erff(y * inv_sqrt2)));
  y = v.z * r * wv.z + bv.z; o.z = f2bf(0.5f * y * (1.0f + erff(y * inv_sqrt2)));
  y = v.w * r * wv.w + bv.w; o.w = f2bf(0.5f * y * (1.0f + erff(y * inv_sqrt2)));

  out_bf16[(size_t)t * (INNER / 4) + j] = o;
}

extern "C" void kernel_launch(void* const* d_in, const int* in_sizes, int n_in,
                              void* d_out, int out_size, void* d_ws, size_t ws_size,
                              hipStream_t stream) {
  const float* state = (const float*)d_in[0];
  const int*   inds  = (const int*)d_in[1];
  const float* emb_w = (const float*)d_in[2];
  const float* proj0 = (const float*)d_in[3];
  const float* projw = (const float*)d_in[4];
  const float* headw = (const float*)d_in[5];
  const float* lnw   = (const float*)d_in[6];
  const float* lnb   = (const float*)d_in[7];
  float* out = (float*)d_out;

  char* ws = (char*)d_ws;
  __hip_bfloat16* stateA = (__hip_bfloat16*)(ws);                    // 1024*4096 bf16
  __hip_bfloat16* stateI = (__hip_bfloat16*)(ws + 8388608);          // 1024*1024 bf16
  float*          nsf    = (float*)        (ws + 10485760);          // 1024*1024 f32
  __hip_bfloat16* p0b    = (__hip_bfloat16*)(ws + 14680064);         // 1024*4096 bf16
  __hip_bfloat16* pwb    = (__hip_bfloat16*)(ws + 23068672);         // 2*1024*1024 bf16
  __hip_bfloat16* hb0    = (__hip_bfloat16*)(ws + 27262976);         // 32000*1024 bf16
  __hip_bfloat16* hb1    = (__hip_bfloat16*)(ws + 92798976);         // 32000*1024 bf16
  // total ws use: 158,334,976 bytes

  double sw = pow(0.5, 1.0 / 6.0);
  float alpha = (float)(sqrt((1.0 - sw * sw) * (INNER / 2.0)) / sw);

  auto cvt = [&](const float* src, __hip_bfloat16* dst, size_t n) {
    int n4 = (int)(n / 4);
    int blocks = (n4 + 255) / 256;
    if (blocks > 2048) blocks = 2048;
    cvt_kernel<<<dim3(blocks), dim3(256), 0, stream>>>((const float4*)src, (ushort4*)dst, n4);
  };

  const int hn4 = (int)((size_t)VOCAB * INNER / 4);

  cvt(state, stateA, (size_t)TOKENS * EMB_DIM);
  cvt(proj0, p0b, (size_t)INNER * EMB_DIM);
  cvt(projw, pwb, (size_t)2 * INNER * INNER);

  // step 0 pre: proj0 GEMM (128 blocks) + cvt head_w[0] -> hb0
  proj_cvt<<<dim3(1024), dim3(256), 0, stream>>>(stateA, p0b, nsf, EMB_DIM,
      (const float4*)headw, (ushort4*)hb0, hn4);
  fuse_ln_gelu<<<dim3(TOKENS), dim3(256), 0, stream>>>(nsf,
      emb_w, inds, lnw, lnb, (ushort4*)stateI, 0, alpha);

  // mega 0: head0 (reads hb0) + proj1 (-> nsf) + cvt head_w[1] -> hb1
  mega<<<dim3(1524), dim3(512), 0, stream>>>(stateI, hb0, out,
      pwb, nsf,
      (const float4*)(headw + (size_t)1 * VOCAB * INNER), (ushort4*)hb1, hn4, 0);
  fuse_ln_gelu<<<dim3(TOKENS), dim3(256), 0, stream>>>(nsf,
      emb_w + (size_t)1 * VOCAB * INNER, inds,
      lnw + INNER, lnb + INNER, (ushort4*)stateI, 1, alpha);

  // mega 1: head1 (reads hb1) + proj2 (-> nsf) + cvt head_w[2] -> hb0
  mega<<<dim3(1524), dim3(512), 0, stream>>>(stateI, hb1, out + (size_t)TOKENS * VOCAB,
      pwb + (size_t)INNER * INNER, nsf,
      (const float4*)(headw + (size_t)2 * VOCAB * INNER), (ushort4*)hb0, hn4, 0);
  fuse_ln_gelu<<<dim3(TOKENS), dim3(256), 0, stream>>>(nsf,
      emb_w + (size_t)2 * VOCAB * INNER, inds,
      lnw + 2 * INNER, lnb + 2 * INNER, (ushort4*)stateI, 2, alpha);

  // mega 2: head2 only (reads hb0); mode=1, grid = 1000
  mega<<<dim3(1000), dim3(512), 0, stream>>>(stateI, hb0, out + (size_t)2 * TOKENS * VOCAB,
      pwb, nsf, (const float4*)headw, (ushort4*)hb1, hn4, 1);
}